// Round 15
// baseline (350.834 us; speedup 1.0000x reference)
//
#include <hip/hip_runtime.h>
#include <hip/hip_bf16.h>
#include <math.h>

// ---------------------------------------------------------------------------
// TernaryLeNet5 forward.
// R29: from R28 (136.7us verified; flag-sync tern234-in-conv12 worked, -7.3).
// Dispatch count 3 -> 2: ALL five tensors' fused pass1+pass2 move into
// conv12 (blocks 0..79; 16/tensor, identical partial structure and index
// order -> delta bit-identical). Image blocks (80..1103) consume w1b/alpha0
// at start and w2b/alpha1 before conv2 via quantize-done flags:
//   producer: quantize stores -> __syncthreads -> t0 __threadfence +
//             release-store MAGIC (agent scope);
//   consumer: 16 threads acquire-spin (+s_sleep) -> __threadfence ->
//             barrier -> plain reads (acquire invalidates stale L2).
// w1 tern is tiny (flag ~1us); w2 tern hides under conv1. Deadlock-free in
// practice: tern blocks have the lowest ids (dispatched first wave), depend
// only on each other; image waits resolve as tern retires.
// conv3fc byte-identical, separate dispatch (1024-thr blocks).
// absmax pinned at 0.00390625 -> no f32 reassociation anywhere.
// Known: ~41us ws-poison fill inside dur_us (uncontrollable); drift ±4us.
// ---------------------------------------------------------------------------

typedef __attribute__((ext_vector_type(8))) short bf16x8;
typedef __attribute__((ext_vector_type(4))) float f32x4;

// ---- ws layout (float offsets) --------------------------------------------
// pb: pabs[5][16] @0, ps1[5][16] @80, pcnt[5][16] @160
static const size_t OFF_PB    = 0;        // 240 f32
static const size_t OFF_W1B   = 256;      // [32][32] bf16 = 512 f32
static const size_t OFF_W2B   = 1056;     // [64][25][32] bf16 = 25600 f32
static const size_t OFF_W3B   = 26656;    // [128][1600] bf16  = 102400 f32
static const size_t OFF_FW1T  = 129056;   // [120][84] f32, +-1/0
static const size_t OFF_FW2T  = 139136;   // [84][10] f32, +-1/0
static const size_t OFF_P2B   = 139976;   // [1024][1600] bf16 = 819200 f32
static const size_t OFF_FLAGS = 959176;   // 160 u32 sync flags (poisoned/iter)
// total ~3.84 MB (ws allocation unchanged, ~4.3 MB)

#define BPT 16     // partial-blocks per tensor
#define MAGIC 0x5A17C0DEu

__device__ __forceinline__ ushort f2bf(float v) {   // RNE float->bf16 bits
    unsigned u = __float_as_uint(v);
    unsigned r = (u + 0x7FFFu + ((u >> 16) & 1u)) >> 16;
    return (ushort)r;
}
__device__ __forceinline__ float bf2f(ushort h) {
    return __uint_as_float((unsigned)h << 16);
}

// tanh via hw exp: 1 - 2e/(1+e), e = exp(-2|x|) in (0,1] -> no overflow.
__device__ __forceinline__ float tanh_fast(float x) {
    float e = __expf(-2.0f * fabsf(x));
    float r = 1.0f - 2.0f * e / (1.0f + e);
    return copysignf(r, x);
}

__device__ __forceinline__ void tensor_select(int tensor,
        const float* w1, const float* w2, const float* w3,
        const float* fw1, const float* fw2,
        const float*& src, int& O, int& K) {
    switch (tensor) {
        case 0: src = w1;  O = 32;  K = 25;   break;
        case 1: src = w2;  O = 64;  K = 800;  break;
        case 2: src = w3;  O = 120; K = 1600; break;
        case 3: src = fw1; O = 84;  K = 120;  break;
        default: src = fw2; O = 10; K = 84;   break;
    }
}

__device__ __forceinline__ float block_sum_256(float v, float* sbuf) {
    #pragma unroll
    for (int off = 32; off > 0; off >>= 1) v += __shfl_down(v, off);
    const int wid = threadIdx.x >> 6;
    if ((threadIdx.x & 63) == 0) sbuf[wid] = v;
    __syncthreads();
    return sbuf[0] + sbuf[1] + sbuf[2] + sbuf[3];
}

// alpha for `tensor` from pass2 partials (redundant per-thread compute)
__device__ __forceinline__ float alpha_of(const float* pb, int tensor) {
    float s1 = 0.f, c = 0.f;
    #pragma unroll
    for (int i = 0; i < BPT; ++i) {
        s1 += pb[80 + tensor * BPT + i];
        c  += pb[160 + tensor * BPT + i];
    }
    return s1 / fmaxf(c, 1.0f);
}

// ---------------------------------------------------------------------------
// Fused ternarize pieces. Phase A: pass1 partial in pass1's EXACT index
// order; publish via agent atomics; spin on own tensor's 16 flags; sum
// partials 0..15 ascending (delta bit-identical to the two-pass version).
__device__ float tern_delta(int tensor, int blk, const float* src, int n,
                            float* pb, unsigned* flags,
                            float* sbuf, float* part) {
    const int t = threadIdx.x;
    float s = 0.f;
    for (int i = blk * 256 + t; i < n; i += BPT * 256) s += fabsf(src[i]);
    s = block_sum_256(s, sbuf);
    if (t == 0) {
        __hip_atomic_store(&pb[tensor * BPT + blk], s,
                           __ATOMIC_RELAXED, __HIP_MEMORY_SCOPE_AGENT);
        __hip_atomic_store(&flags[tensor * BPT + blk], MAGIC,
                           __ATOMIC_RELEASE, __HIP_MEMORY_SCOPE_AGENT);
    }
    if (t < BPT) {
        while (__hip_atomic_load(&flags[tensor * BPT + t],
                                 __ATOMIC_ACQUIRE, __HIP_MEMORY_SCOPE_AGENT)
               != MAGIC) {}
        part[t] = __hip_atomic_load(&pb[tensor * BPT + t],
                                    __ATOMIC_RELAXED, __HIP_MEMORY_SCOPE_AGENT);
    }
    __syncthreads();
    float tot = 0.f;
    #pragma unroll
    for (int i = 0; i < BPT; ++i) tot += part[i];
    return 0.7f * tot / (float)n;
}

// Phase B: pass2 quantize body (identical to the two-pass version).
__device__ void tern_quantize(int tensor, int blk, const float* src, int n,
                              int O, int K, float delta,
                              ushort* w1b, ushort* w2b, ushort* w3b,
                              float* fw1t, float* fw2t, float* pb,
                              float* sbuf) {
    const int t = threadIdx.x;
    const ushort BP = 0x3F80u, BN = 0xBF80u;   // bf16 +1, -1
    float s1 = 0.f, cnt = 0.f;

    if (tensor == 0) {
        // w1 -> bf16 [oc][32]: k 0..24 = taps, k 25..31 = 0 (pads MFMA K)
        for (int j = blk * 256 + t; j < 1024; j += BPT * 256) {
            const int oc = j >> 5, kk = j & 31;
            ushort qb = 0;
            if (kk < 25) {
                float w = src[oc * 25 + kk];
                float aw = fabsf(w);
                if (aw > delta) { s1 += aw; cnt += 1.f; qb = (w > 0.f) ? BP : BN; }
            }
            w1b[j] = qb;
        }
    } else if (tensor == 2) {
        // w3 -> bf16 [oc][1600] row-linear; zero-fill pad rows 120..127
        for (int i = blk * 256 + t; i < 128 * 1600; i += BPT * 256) {
            ushort qb = 0;
            if (i < n) {
                float w = src[i];
                float aw = fabsf(w);
                if (aw > delta) { s1 += aw; cnt += 1.f; qb = (w > 0.f) ? BP : BN; }
            }
            w3b[i] = qb;
        }
    } else if (tensor == 1) {
        // w2 -> bf16 [oc][tap][ic]; src is [oc][ic][kh][kw]
        for (int i = blk * 256 + t; i < n; i += BPT * 256) {
            float w = src[i];
            float aw = fabsf(w);
            ushort qb = 0;
            if (aw > delta) { s1 += aw; cnt += 1.f; qb = (w > 0.f) ? BP : BN; }
            int oc = i / 800;
            int r  = i - oc * 800;
            int ic = r / 25;
            int tap = r - ic * 25;
            w2b[oc * 800 + tap * 32 + ic] = qb;
        }
    } else {
        float* dst = (tensor == 3) ? fw1t : fw2t;
        for (int i = blk * 256 + t; i < n; i += BPT * 256) {
            float w = src[i];
            float aw = fabsf(w);
            float q = 0.f;
            if (aw > delta) { s1 += aw; cnt += 1.f; q = (w > 0.f) ? 1.f : -1.f; }
            int o = i / K;
            int k = i - o * K;
            dst[k * O + o] = q;      // transpose to [k][O]
        }
    }
    __syncthreads();
    s1 = block_sum_256(s1, sbuf);
    __syncthreads();
    cnt = block_sum_256(cnt, sbuf);
    if (t == 0) {
        pb[80 + tensor * BPT + blk]  = s1;
        pb[160 + tensor * BPT + blk] = cnt;
    }
}

// ---------------------------------------------------------------------------
// conv2 MFMA inner, tap-outer with explicit depth-4 register prefetch of the
// B fragments (w2b, L2-resident). Per-acc tap order 0..24 preserved:
// bit-exact. M is Z-ordered (2x2 pool windows).
#define C2PF 4
__device__ __forceinline__ void conv2_all(
        const ushort* __restrict__ w2b, const ushort* sxt,
        int n0, int mt0, int lane, f32x4 acc[4][2]) {
    const int col = lane & 15, quad = lane >> 4;
    const ushort* abase[4];
    #pragma unroll
    for (int mi = 0; mi < 4; ++mi) {
        int m = (mt0 + mi) * 16 + col;
        m = m < 100 ? m : 99;                     // clamp padding rows
        const int pb25 = m >> 2, sub = m & 3;
        const int oh = 2 * (pb25 / 5) + (sub >> 1);
        const int ow = 2 * (pb25 % 5) + (sub & 1);
        abase[mi] = sxt + (oh * 14 + ow) * 40 + quad * 8;
    }
    const ushort* wb0 = w2b + (size_t)(n0 + col) * 800 + quad * 8;
    const ushort* wb1 = wb0 + 16 * 800;
    bf16x8 pb0[C2PF], pb1[C2PF];
    #pragma unroll
    for (int i = 0; i < C2PF; ++i) {
        pb0[i] = *(const bf16x8*)(wb0 + i * 32);
        pb1[i] = *(const bf16x8*)(wb1 + i * 32);
    }
    #pragma unroll
    for (int tap = 0; tap < 25; ++tap) {
        const int slot = tap & (C2PF - 1);        // static after full unroll
        const bf16x8 b0 = pb0[slot];
        const bf16x8 b1 = pb1[slot];
        if (tap + C2PF < 25) {
            pb0[slot] = *(const bf16x8*)(wb0 + (tap + C2PF) * 32);
            pb1[slot] = *(const bf16x8*)(wb1 + (tap + C2PF) * 32);
        }
        const int kh = tap / 5, kw = tap - kh * 5;
        const int aoff = (kh * 14 + kw) * 40;
        #pragma unroll
        for (int mi = 0; mi < 4; ++mi) {
            bf16x8 af = *(const bf16x8*)(abase[mi] + aoff);
            acc[mi][0] = __builtin_amdgcn_mfma_f32_16x16x32_bf16(af, b0, acc[mi][0], 0, 0, 0);
            acc[mi][1] = __builtin_amdgcn_mfma_f32_16x16x32_bf16(af, b1, acc[mi][1], 0, 0, 0);
        }
    }
}

// ---------------------------------------------------------------------------
// conv12: blocks 0..79 = fused pass1+pass2 for ALL tensors 0..4 (+ done
// flags); blocks 80..1103 = image pipeline, gated on w1-done at start and
// w2-done before conv2. LDS: sxt @0 (15680B), sxb @15680 (2048B),
// salpha @17728 -> ~17.7KB; 4 blocks/CU.
__global__ __launch_bounds__(256, 4)
void conv12_kernel(const float* __restrict__ x,
                   const float* __restrict__ w1, const float* __restrict__ w2,
                   const float* __restrict__ w3, const float* __restrict__ fw1,
                   const float* __restrict__ fw2,
                   const float* __restrict__ b1, const float* __restrict__ b2,
                   float* __restrict__ pb, ushort* __restrict__ p2b,
                   ushort* __restrict__ w1b, ushort* __restrict__ w2b,
                   ushort* __restrict__ w3b, float* __restrict__ fw1t,
                   float* __restrict__ fw2t, unsigned* __restrict__ flags) {
    __shared__ __align__(16) char smem[17744];
    ushort* sxt    = (ushort*)smem;
    ushort* sxb    = (ushort*)(smem + 15680);
    float*  salpha = (float*) (smem + 17728);

    const int t = threadIdx.x;

    if (blockIdx.x < 80) {   // ---- tern blocks: tensors 0..4 -------------
        float* sbuf = (float*)smem;
        float* part = (float*)(smem + 16);
        const int b = blockIdx.x;
        const int tensor = b >> 4;
        const int blk = b & 15;
        const float* src; int O, K;
        tensor_select(tensor, w1, w2, w3, fw1, fw2, src, O, K);
        const int n2 = O * K;
        const float delta = tern_delta(tensor, blk, src, n2, pb, flags, sbuf, part);
        tern_quantize(tensor, blk, src, n2, O, K, delta,
                      w1b, w2b, w3b, fw1t, fw2t, pb, sbuf);
        __syncthreads();
        if (t == 0) {
            __threadfence();
            __hip_atomic_store(&flags[80 + tensor * BPT + blk], MAGIC,
                               __ATOMIC_RELEASE, __HIP_MEMORY_SCOPE_AGENT);
        }
        return;
    }

    const int n = blockIdx.x - 80;
    const int wave = t >> 6, lane = t & 63;
    const int col = lane & 15, quad = lane >> 4;

    // ---- wait for w1 ternarize (tensor 0) ------------------------------
    if (t < BPT) {
        while (__hip_atomic_load(&flags[80 + t],
                                 __ATOMIC_ACQUIRE, __HIP_MEMORY_SCOPE_AGENT)
               != MAGIC)
            __builtin_amdgcn_s_sleep(8);
        __threadfence();
    }
    __syncthreads();

    bf16x8 B0 = *(const bf16x8*)(w1b + col * 32 + quad * 8);
    bf16x8 B1 = *(const bf16x8*)(w1b + (col + 16) * 32 + quad * 8);
    const float b1a = b1[col];
    const float b1b = b1[col + 16];

    {   // stage x -> bf16 sxb
        float4 v = ((const float4*)(x + (size_t)n * 1024))[t];
        ushort4 q;
        q.x = f2bf(v.x); q.y = f2bf(v.y); q.z = f2bf(v.z); q.w = f2bf(v.w);
        *(ushort4*)(sxb + t * 4) = q;
        if (t == 0) salpha[0] = alpha_of(pb, 0);
    }
    __syncthreads();

    // ---- conv1: 49 tiles, direct A-build, Z-ordered positions -----------
    {
        const float a1 = salpha[0];
        const int sub  = col & 3;
        const int colq = col >> 2;
        const int soff = ((sub >> 1) << 5) + (sub & 1);   // oh,ow sub-offset
        int woff[8];
        #pragma unroll
        for (int j = 0; j < 8; ++j) {
            const int tap = quad * 8 + j;
            woff[j] = (tap < 25) ? ((tap / 5) << 5) + (tap % 5) : 0;
        }
        const unsigned kmask = (quad == 3) ? 0u : 0xFFFFFFFFu;

        for (int tl = wave; tl < 49; tl += 4) {
            const int pb4 = tl * 4 + colq;                // pool block 0..195
            const int bh  = (pb4 * 4682) >> 16;           // pb4 / 14
            const int bw  = pb4 - bh * 14;
            const int base = (bh << 6) + (bw << 1) + soff; // oh*32 + ow
            unsigned v0 = sxb[base + woff[0]];
            unsigned v1 = sxb[base + woff[1]] & kmask;
            unsigned v2 = sxb[base + woff[2]] & kmask;
            unsigned v3 = sxb[base + woff[3]] & kmask;
            unsigned v4 = sxb[base + woff[4]] & kmask;
            unsigned v5 = sxb[base + woff[5]] & kmask;
            unsigned v6 = sxb[base + woff[6]] & kmask;
            unsigned v7 = sxb[base + woff[7]] & kmask;
            uint4 u;
            u.x = v0 | (v1 << 16);
            u.y = v2 | (v3 << 16);
            u.z = v4 | (v5 << 16);
            u.w = v6 | (v7 << 16);
            const bf16x8 af = *(const bf16x8*)&u;
            f32x4 z = {};
            f32x4 c0 = __builtin_amdgcn_mfma_f32_16x16x32_bf16(af, B0, z, 0, 0, 0);
            f32x4 c1 = __builtin_amdgcn_mfma_f32_16x16x32_bf16(af, B1, z, 0, 0, 0);
            // quad's 4 C-rows = one 2x2 pool window (subs 0..3); bf16-round
            // the h-pool maxima first (bit-exact), then v-max, alpha/bias/tanh.
            const int pos2 = tl * 4 + quad;
            const float h01 = bf2f(f2bf(fmaxf(c0[0], c0[1])));
            const float h23 = bf2f(f2bf(fmaxf(c0[2], c0[3])));
            sxt[pos2 * 40 + col] =
                f2bf(tanh_fast(fmaf(a1, fmaxf(h01, h23), b1a)));
            const float g01 = bf2f(f2bf(fmaxf(c1[0], c1[1])));
            const float g23 = bf2f(f2bf(fmaxf(c1[2], c1[3])));
            sxt[pos2 * 40 + col + 16] =
                f2bf(tanh_fast(fmaf(a1, fmaxf(g01, g23), b1b)));
        }
    }
    __syncthreads();

    // ---- wait for w2 ternarize (tensor 1); load alpha1 ------------------
    if (t < BPT) {
        while (__hip_atomic_load(&flags[80 + BPT + t],
                                 __ATOMIC_ACQUIRE, __HIP_MEMORY_SCOPE_AGENT)
               != MAGIC)
            __builtin_amdgcn_s_sleep(8);
        __threadfence();
    }
    __syncthreads();
    if (t == 0) salpha[1] = alpha_of(pb, 1);
    __syncthreads();

    // ---- conv2 MFMA (Z-ordered M) + fused pool/alpha/bias/tanh -> p2b ---
    const int n0  = (wave & 1) * 32;
    const int mt0 = (wave >> 1) * 4;
    f32x4 acc2[4][2] = {};
    conv2_all(w2b, sxt, n0, mt0, lane, acc2);

    {   // quad's 4 C-rows = one 2x2 pool window; chain
        // fmax(fmax(a0,a1), fmax(a2,a3)) identical to old hb2 path.
        const float a2 = salpha[1];
        const float b2a = b2[n0 + col];
        const float b2b = b2[n0 + 16 + col];
        ushort* prow = p2b + (size_t)n * 1600;
        #pragma unroll
        for (int mi = 0; mi < 4; ++mi) {
            const int pb25 = (mt0 + mi) * 4 + quad;
            if (pb25 < 25) {
                #pragma unroll
                for (int np = 0; np < 2; ++np) {
                    const float p01 = fmaxf(acc2[mi][np][0], acc2[mi][np][1]);
                    const float p23 = fmaxf(acc2[mi][np][2], acc2[mi][np][3]);
                    const float pooled = fmaxf(p01, p23);
                    const int oc = n0 + np * 16 + col;
                    const float bb = np ? b2b : b2a;
                    prow[oc * 25 + pb25] =
                        f2bf(tanh_fast(fmaf(a2, pooled, bb)));
                }
            }
        }
    }
}

// ---------------------------------------------------------------------------
// conv3fc v3: fused conv3 GEMM + fc1 + fc2 + softmax. 128 blocks x 1024 thr
// x 8 imgs (lanes 0..31 valid; pad lanes clamped — MFMA C-rows independent,
// valid rows bit-exact). SAME 13/13/12/12 K-chains and red-sum order.
// red lane-major [kg][nt][r][lane]: conflict-free. LDS ~80KB, 128 CUs busy.
__global__ __launch_bounds__(1024)
void conv3fc_kernel(const ushort* __restrict__ p2b, const ushort* __restrict__ w3b,
                    const float* __restrict__ b3, const float* __restrict__ pb,
                    const float* __restrict__ fw1t, const float* __restrict__ fb1,
                    const float* __restrict__ fw2t, const float* __restrict__ fb2,
                    float* __restrict__ out) {
    __shared__ __align__(16) char redmem[32768];     // red[4][8][4][64] f32
    __shared__ __align__(16) float h3s[8][120];
    __shared__ __align__(16) float fw1s[120 * 84];
    __shared__ __align__(16) float fw2s[84 * 10];
    __shared__ float salpha[3];
    float (*red)[8][4][64] = (float (*)[8][4][64])redmem;  // [kg][nt][r][lane]
    float* sh4 = (float*)redmem;                     // [8][84] overlay
    float* sl  = (float*)(redmem + 8 * 84 * 4);      // [8][10] overlay

    const int t = threadIdx.x;
    const int wave = t >> 6, lane = t & 63;
    const int col = lane & 15, quad = lane >> 4;
    const int img0 = blockIdx.x * 8;
    const int kg  = wave & 3;       // K-split index (sum order 0..3)
    const int ntg = wave >> 2;      // handles nt = ntg*2, ntg*2+1

    // stage fc weights (visibility covered by the post-conv3 barrier)
    for (int i = t; i < 2520; i += 1024)
        ((float4*)fw1s)[i] = ((const float4*)fw1t)[i];
    if (t < 210) ((float4*)fw2s)[t] = ((const float4*)fw2t)[t];
    if (t == 0) salpha[0] = alpha_of(pb, 2);
    if (t == 1) salpha[1] = alpha_of(pb, 3);
    if (t == 2) salpha[2] = alpha_of(pb, 4);

    // ---- conv3 MFMA: 8 imgs (+8 pad rows) x 2 nt-tiles per wave ---------
    const int kstart = (kg < 2) ? kg * 13 : 26 + (kg - 2) * 12;  // 0,13,26,38
    const int steps  = (kg < 2) ? 13 : 12;
    const int acol   = (col < 8) ? col : 7;          // clamp pad images
    const ushort* Abase = p2b + (size_t)(img0 + acol) * 1600 + kstart * 32 + quad * 8;

    f32x4 acc[2] = {};
    {
        const int nt0 = ntg * 2;
        const ushort* Bb0 = w3b + (size_t)(nt0 * 16 + col) * 1600 + kstart * 32 + quad * 8;
        const ushort* Bb1 = Bb0 + (size_t)16 * 1600;
        for (int s = 0; s < steps; ++s) {
            const bf16x8 af = *(const bf16x8*)(Abase + s * 32);
            const bf16x8 b0 = *(const bf16x8*)(Bb0 + s * 32);
            const bf16x8 b1 = *(const bf16x8*)(Bb1 + s * 32);
            acc[0] = __builtin_amdgcn_mfma_f32_16x16x32_bf16(af, b0, acc[0], 0, 0, 0);
            acc[1] = __builtin_amdgcn_mfma_f32_16x16x32_bf16(af, b1, acc[1], 0, 0, 0);
        }
        #pragma unroll
        for (int j = 0; j < 2; ++j)
            #pragma unroll
            for (int r = 0; r < 4; ++r)
                red[kg][nt0 + j][r][lane] = acc[j][r];
    }
    __syncthreads();

    // ---- cross-wave reduce + alpha/bias/tanh -> h3s ---------------------
    {
        const float a3 = salpha[0];
        const int nt  = t >> 7;
        const int rem = t & 127;
        const int vh  = rem >> 5;
        const int l   = rem & 31;              // lanes 0..31
        const int img = ((l >> 4) << 2) + vh;  // 0..7
        const int oc  = (nt << 4) + (l & 15);
        if (oc < 120) {
            float s = red[0][nt][vh][l] + red[1][nt][vh][l]
                    + red[2][nt][vh][l] + red[3][nt][vh][l];
            h3s[img][oc] = tanh_fast(fmaf(a3, s, b3[oc]));
        }
    }
    __syncthreads();

    // ---- fc1: 672 tasks (8 img x 84 oc), k 0..119 ascending -------------
    if (t < 672) {
        const float af1 = salpha[1];
        const int img = t / 84, oc = t - img * 84;
        float a = 0.f;
        #pragma unroll 4
        for (int k = 0; k < 120; ++k)
            a = fmaf(fw1s[k * 84 + oc], h3s[img][k], a);
        sh4[img * 84 + oc] = tanh_fast(fmaf(af1, a, fb1[oc]));
    }
    __syncthreads();

    // ---- fc2 + logits ---------------------------------------------------
    if (t < 80) {
        const float af2 = salpha[2];
        const int img = t / 10, oc = t - img * 10;
        float a2 = 0.f;
        #pragma unroll 4
        for (int k = 0; k < 84; ++k)
            a2 = fmaf(fw2s[k * 10 + oc], sh4[img * 84 + k], a2);
        const float lg = fmaf(af2, a2, fb2[oc]);
        sl[img * 10 + oc] = lg;
        out[(size_t)(img0 + img) * 10 + oc] = lg;
    }
    __syncthreads();

    // ---- softmax --------------------------------------------------------
    if (t < 80) {
        const int img = t / 10, oc = t - img * 10;
        float m = -INFINITY;
        #pragma unroll
        for (int i = 0; i < 10; ++i) m = fmaxf(m, sl[img * 10 + i]);
        float s = 0.f;
        #pragma unroll
        for (int i = 0; i < 10; ++i) s += expf(sl[img * 10 + i] - m);
        out[10240 + (size_t)(img0 + img) * 10 + oc] = expf(sl[img * 10 + oc] - m) / s;
    }
}

// ---------------------------------------------------------------------------
extern "C" void kernel_launch(void* const* d_in, const int* in_sizes, int n_in,
                              void* d_out, int out_size, void* d_ws, size_t ws_size,
                              hipStream_t stream) {
    const float* x   = (const float*)d_in[0];
    const float* w1  = (const float*)d_in[1];
    const float* b1  = (const float*)d_in[2];
    const float* w2  = (const float*)d_in[3];
    const float* b2  = (const float*)d_in[4];
    const float* w3  = (const float*)d_in[5];
    const float* b3  = (const float*)d_in[6];
    const float* fw1 = (const float*)d_in[7];
    const float* fb1 = (const float*)d_in[8];
    const float* fw2 = (const float*)d_in[9];
    const float* fb2 = (const float*)d_in[10];

    float* ws = (float*)d_ws;
    float*    pb    = ws + OFF_PB;
    ushort*   w1b   = (ushort*)(ws + OFF_W1B);
    ushort*   w2b   = (ushort*)(ws + OFF_W2B);
    ushort*   w3b   = (ushort*)(ws + OFF_W3B);
    float*    fw1t  = ws + OFF_FW1T;
    float*    fw2t  = ws + OFF_FW2T;
    ushort*   p2b   = (ushort*)(ws + OFF_P2B);
    unsigned* flags = (unsigned*)(ws + OFF_FLAGS);
    float*    out   = (float*)d_out;

    conv12_kernel<<<1104, 256, 0, stream>>>(x, w1, w2, w3, fw1, fw2, b1, b2,
                                            pb, p2b, w1b, w2b, w3b, fw1t,
                                            fw2t, flags);
    conv3fc_kernel<<<128, 1024, 0, stream>>>(p2b, w3b, b3, pb,
                                             fw1t, fb1, fw2t, fb2, out);
}

// Round 16
// 135.617 us; speedup vs baseline: 2.5870x; 2.5870x over previous
//
#include <hip/hip_runtime.h>
#include <hip/hip_bf16.h>
#include <math.h>

// ---------------------------------------------------------------------------
// TernaryLeNet5 forward.
// R30: REVERT to R28 byte-exact (verified 136.7us session best). R29's
// all-tern-in-conv12 was a 214us regression: 944 image blocks x 16 lanes
// agent-scope spinning on ONE 64B flag line starved the tern producers
// (conv12 276us/dispatch, MfmaUtil 2%, Occ 48% = all waiting). Lesson:
// intra-grid flag-sync is safe only with FEW waiters (R28: 48 tern blocks
// waiting on each other; image blocks never wait). Spin-storms invert
// priority at scale.
// R28 structure (3 dispatches):
//  - tern01_kernel (32 blk): fused pass1+pass2 for w1,w2 (flag-sync among
//    16 blocks/tensor; pass1 partials in EXACT pass1 index order -> delta
//    bit-identical).
//  - conv12 (1072 blk): blocks 0..47 fused tern for w3,fw1,fw2; blocks
//    48..1071 image pipeline (direct-A conv1 + Z-ordered conv2, pools fused
//    in MFMA epilogues, 2 barriers). Image blocks never wait.
//  - conv3fc (128 blk x 1024 thr x 8 imgs).
// absmax pinned at 0.00390625 -> no f32 reassociation anywhere.
// Known: ~41us ws-poison fill inside dur_us (uncontrollable); drift ±4us.
// ---------------------------------------------------------------------------

typedef __attribute__((ext_vector_type(8))) short bf16x8;
typedef __attribute__((ext_vector_type(4))) float f32x4;

// ---- ws layout (float offsets) --------------------------------------------
// pb: pabs[5][16] @0, ps1[5][16] @80, pcnt[5][16] @160
static const size_t OFF_PB    = 0;        // 240 f32
static const size_t OFF_W1B   = 256;      // [32][32] bf16 = 512 f32
static const size_t OFF_W2B   = 1056;     // [64][25][32] bf16 = 25600 f32
static const size_t OFF_W3B   = 26656;    // [128][1600] bf16  = 102400 f32
static const size_t OFF_FW1T  = 129056;   // [120][84] f32, +-1/0
static const size_t OFF_FW2T  = 139136;   // [84][10] f32, +-1/0
static const size_t OFF_P2B   = 139976;   // [1024][1600] bf16 = 819200 f32
static const size_t OFF_FLAGS = 959176;   // 80 u32 sync flags (poisoned/iter)
// total ~3.84 MB (ws allocation unchanged, ~4.3 MB)

#define BPT 16     // partial-blocks per tensor
#define MAGIC 0x5A17C0DEu

__device__ __forceinline__ ushort f2bf(float v) {   // RNE float->bf16 bits
    unsigned u = __float_as_uint(v);
    unsigned r = (u + 0x7FFFu + ((u >> 16) & 1u)) >> 16;
    return (ushort)r;
}
__device__ __forceinline__ float bf2f(ushort h) {
    return __uint_as_float((unsigned)h << 16);
}

// tanh via hw exp: 1 - 2e/(1+e), e = exp(-2|x|) in (0,1] -> no overflow.
__device__ __forceinline__ float tanh_fast(float x) {
    float e = __expf(-2.0f * fabsf(x));
    float r = 1.0f - 2.0f * e / (1.0f + e);
    return copysignf(r, x);
}

__device__ __forceinline__ void tensor_select(int tensor,
        const float* w1, const float* w2, const float* w3,
        const float* fw1, const float* fw2,
        const float*& src, int& O, int& K) {
    switch (tensor) {
        case 0: src = w1;  O = 32;  K = 25;   break;
        case 1: src = w2;  O = 64;  K = 800;  break;
        case 2: src = w3;  O = 120; K = 1600; break;
        case 3: src = fw1; O = 84;  K = 120;  break;
        default: src = fw2; O = 10; K = 84;   break;
    }
}

__device__ __forceinline__ float block_sum_256(float v, float* sbuf) {
    #pragma unroll
    for (int off = 32; off > 0; off >>= 1) v += __shfl_down(v, off);
    const int wid = threadIdx.x >> 6;
    if ((threadIdx.x & 63) == 0) sbuf[wid] = v;
    __syncthreads();
    return sbuf[0] + sbuf[1] + sbuf[2] + sbuf[3];
}

// alpha for `tensor` from pass2 partials (redundant per-thread compute)
__device__ __forceinline__ float alpha_of(const float* pb, int tensor) {
    float s1 = 0.f, c = 0.f;
    #pragma unroll
    for (int i = 0; i < BPT; ++i) {
        s1 += pb[80 + tensor * BPT + i];
        c  += pb[160 + tensor * BPT + i];
    }
    return s1 / fmaxf(c, 1.0f);
}

// ---------------------------------------------------------------------------
// Fused ternarize pieces (shared by tern01_kernel and conv12's tern tail).
// Phase A: pass1 partial in pass1's EXACT index order; publish via agent
// atomics; spin on own tensor's 16 flags; sum partials 0..15 ascending.
__device__ float tern_delta(int tensor, int blk, const float* src, int n,
                            float* pb, unsigned* flags,
                            float* sbuf, float* part) {
    const int t = threadIdx.x;
    float s = 0.f;
    for (int i = blk * 256 + t; i < n; i += BPT * 256) s += fabsf(src[i]);
    s = block_sum_256(s, sbuf);
    if (t == 0) {
        __hip_atomic_store(&pb[tensor * BPT + blk], s,
                           __ATOMIC_RELAXED, __HIP_MEMORY_SCOPE_AGENT);
        __hip_atomic_store(&flags[tensor * BPT + blk], MAGIC,
                           __ATOMIC_RELEASE, __HIP_MEMORY_SCOPE_AGENT);
    }
    if (t < BPT) {
        while (__hip_atomic_load(&flags[tensor * BPT + t],
                                 __ATOMIC_ACQUIRE, __HIP_MEMORY_SCOPE_AGENT)
               != MAGIC) {}
        part[t] = __hip_atomic_load(&pb[tensor * BPT + t],
                                    __ATOMIC_RELAXED, __HIP_MEMORY_SCOPE_AGENT);
    }
    __syncthreads();
    float tot = 0.f;
    #pragma unroll
    for (int i = 0; i < BPT; ++i) tot += part[i];
    return 0.7f * tot / (float)n;
}

// Phase B: pass2 quantize body (identical to the two-pass version).
__device__ void tern_quantize(int tensor, int blk, const float* src, int n,
                              int O, int K, float delta,
                              ushort* w1b, ushort* w2b, ushort* w3b,
                              float* fw1t, float* fw2t, float* pb,
                              float* sbuf) {
    const int t = threadIdx.x;
    const ushort BP = 0x3F80u, BN = 0xBF80u;   // bf16 +1, -1
    float s1 = 0.f, cnt = 0.f;

    if (tensor == 0) {
        // w1 -> bf16 [oc][32]: k 0..24 = taps, k 25..31 = 0 (pads MFMA K)
        for (int j = blk * 256 + t; j < 1024; j += BPT * 256) {
            const int oc = j >> 5, kk = j & 31;
            ushort qb = 0;
            if (kk < 25) {
                float w = src[oc * 25 + kk];
                float aw = fabsf(w);
                if (aw > delta) { s1 += aw; cnt += 1.f; qb = (w > 0.f) ? BP : BN; }
            }
            w1b[j] = qb;
        }
    } else if (tensor == 2) {
        // w3 -> bf16 [oc][1600] row-linear; zero-fill pad rows 120..127
        for (int i = blk * 256 + t; i < 128 * 1600; i += BPT * 256) {
            ushort qb = 0;
            if (i < n) {
                float w = src[i];
                float aw = fabsf(w);
                if (aw > delta) { s1 += aw; cnt += 1.f; qb = (w > 0.f) ? BP : BN; }
            }
            w3b[i] = qb;
        }
    } else if (tensor == 1) {
        // w2 -> bf16 [oc][tap][ic]; src is [oc][ic][kh][kw]
        for (int i = blk * 256 + t; i < n; i += BPT * 256) {
            float w = src[i];
            float aw = fabsf(w);
            ushort qb = 0;
            if (aw > delta) { s1 += aw; cnt += 1.f; qb = (w > 0.f) ? BP : BN; }
            int oc = i / 800;
            int r  = i - oc * 800;
            int ic = r / 25;
            int tap = r - ic * 25;
            w2b[oc * 800 + tap * 32 + ic] = qb;
        }
    } else {
        float* dst = (tensor == 3) ? fw1t : fw2t;
        for (int i = blk * 256 + t; i < n; i += BPT * 256) {
            float w = src[i];
            float aw = fabsf(w);
            float q = 0.f;
            if (aw > delta) { s1 += aw; cnt += 1.f; q = (w > 0.f) ? 1.f : -1.f; }
            int o = i / K;
            int k = i - o * K;
            dst[k * O + o] = q;      // transpose to [k][O]
        }
    }
    __syncthreads();
    s1 = block_sum_256(s1, sbuf);
    __syncthreads();
    cnt = block_sum_256(cnt, sbuf);
    if (t == 0) {
        pb[80 + tensor * BPT + blk]  = s1;
        pb[160 + tensor * BPT + blk] = cnt;
    }
}

// ---------------------------------------------------------------------------
// tern01: fused pass1+pass2 for tensors 0 (w1) and 1 (w2). 32 blocks.
__global__ __launch_bounds__(256)
void tern01_kernel(const float* w1, const float* w2,
                   ushort* w1b, ushort* w2b, float* pb, unsigned* flags) {
    __shared__ float sbuf[4];
    __shared__ float part[BPT];
    const int tensor = blockIdx.x >> 4;    // 0 or 1
    const int blk    = blockIdx.x & 15;
    const float* src; int O, K;
    tensor_select(tensor, w1, w2, nullptr, nullptr, nullptr, src, O, K);
    const int n = O * K;
    const float delta = tern_delta(tensor, blk, src, n, pb, flags, sbuf, part);
    tern_quantize(tensor, blk, src, n, O, K, delta,
                  w1b, w2b, nullptr, nullptr, nullptr, pb, sbuf);
}

// ---------------------------------------------------------------------------
// conv2 MFMA inner, tap-outer with explicit depth-4 register prefetch of the
// B fragments (w2b, L2-resident). Per-acc tap order 0..24 preserved:
// bit-exact. M is Z-ordered (2x2 pool windows).
#define C2PF 4
__device__ __forceinline__ void conv2_all(
        const ushort* __restrict__ w2b, const ushort* sxt,
        int n0, int mt0, int lane, f32x4 acc[4][2]) {
    const int col = lane & 15, quad = lane >> 4;
    const ushort* abase[4];
    #pragma unroll
    for (int mi = 0; mi < 4; ++mi) {
        int m = (mt0 + mi) * 16 + col;
        m = m < 100 ? m : 99;                     // clamp padding rows
        const int pb25 = m >> 2, sub = m & 3;
        const int oh = 2 * (pb25 / 5) + (sub >> 1);
        const int ow = 2 * (pb25 % 5) + (sub & 1);
        abase[mi] = sxt + (oh * 14 + ow) * 40 + quad * 8;
    }
    const ushort* wb0 = w2b + (size_t)(n0 + col) * 800 + quad * 8;
    const ushort* wb1 = wb0 + 16 * 800;
    bf16x8 pb0[C2PF], pb1[C2PF];
    #pragma unroll
    for (int i = 0; i < C2PF; ++i) {
        pb0[i] = *(const bf16x8*)(wb0 + i * 32);
        pb1[i] = *(const bf16x8*)(wb1 + i * 32);
    }
    #pragma unroll
    for (int tap = 0; tap < 25; ++tap) {
        const int slot = tap & (C2PF - 1);        // static after full unroll
        const bf16x8 b0 = pb0[slot];
        const bf16x8 b1 = pb1[slot];
        if (tap + C2PF < 25) {
            pb0[slot] = *(const bf16x8*)(wb0 + (tap + C2PF) * 32);
            pb1[slot] = *(const bf16x8*)(wb1 + (tap + C2PF) * 32);
        }
        const int kh = tap / 5, kw = tap - kh * 5;
        const int aoff = (kh * 14 + kw) * 40;
        #pragma unroll
        for (int mi = 0; mi < 4; ++mi) {
            bf16x8 af = *(const bf16x8*)(abase[mi] + aoff);
            acc[mi][0] = __builtin_amdgcn_mfma_f32_16x16x32_bf16(af, b0, acc[mi][0], 0, 0, 0);
            acc[mi][1] = __builtin_amdgcn_mfma_f32_16x16x32_bf16(af, b1, acc[mi][1], 0, 0, 0);
        }
    }
}

// ---------------------------------------------------------------------------
// conv12: blocks 0..47 = fused pass1+pass2 for tensors 2,3,4 (hidden under
// the image work); blocks 48..1071 = image pipeline (direct-A conv1 + fused
// pool epilogue, Z-ordered conv2 + fused pool epilogue). 2 barriers.
// Image blocks never wait on flags (deadlock/spin-storm-free).
// LDS: sxt @0 (15680B), sxb @15680 (2048B), salpha @17728 -> ~17.7KB.
__global__ __launch_bounds__(256, 4)
void conv12_kernel(const float* __restrict__ x, const ushort* __restrict__ w1b,
                   const float* __restrict__ b1, const ushort* __restrict__ w2b,
                   const float* __restrict__ b2, float* __restrict__ pb,
                   ushort* __restrict__ p2b,
                   const float* __restrict__ w3, const float* __restrict__ fw1,
                   const float* __restrict__ fw2, ushort* __restrict__ w3b,
                   float* __restrict__ fw1t, float* __restrict__ fw2t,
                   unsigned* __restrict__ flags) {
    __shared__ __align__(16) char smem[17744];
    ushort* sxt    = (ushort*)smem;
    ushort* sxb    = (ushort*)(smem + 15680);
    float*  salpha = (float*) (smem + 17728);

    if (blockIdx.x < 48) {   // ---- tern tail: tensors 2,3,4 --------------
        float* sbuf = (float*)smem;
        float* part = (float*)(smem + 16);
        const int b = blockIdx.x;
        const int tensor = 2 + (b >> 4);
        const int blk = b & 15;
        const float* src; int O, K;
        tensor_select(tensor, nullptr, nullptr, w3, fw1, fw2, src, O, K);
        const int n2 = O * K;
        const float delta = tern_delta(tensor, blk, src, n2, pb, flags, sbuf, part);
        tern_quantize(tensor, blk, src, n2, O, K, delta,
                      nullptr, nullptr, w3b, fw1t, fw2t, pb, sbuf);
        return;
    }

    const int n = blockIdx.x - 48;
    const int t = threadIdx.x;
    const int wave = t >> 6, lane = t & 63;
    const int col = lane & 15, quad = lane >> 4;

    bf16x8 B0 = *(const bf16x8*)(w1b + col * 32 + quad * 8);
    bf16x8 B1 = *(const bf16x8*)(w1b + (col + 16) * 32 + quad * 8);
    const float b1a = b1[col];
    const float b1b = b1[col + 16];

    {   // stage x -> bf16 sxb
        float4 v = ((const float4*)(x + (size_t)n * 1024))[t];
        ushort4 q;
        q.x = f2bf(v.x); q.y = f2bf(v.y); q.z = f2bf(v.z); q.w = f2bf(v.w);
        *(ushort4*)(sxb + t * 4) = q;
        if (t == 0) salpha[0] = alpha_of(pb, 0);
        if (t == 1) salpha[1] = alpha_of(pb, 1);
    }
    __syncthreads();

    // ---- conv1: 49 tiles, direct A-build, Z-ordered positions -----------
    {
        const float a1 = salpha[0];
        const int sub  = col & 3;
        const int colq = col >> 2;
        const int soff = ((sub >> 1) << 5) + (sub & 1);   // oh,ow sub-offset
        int woff[8];
        #pragma unroll
        for (int j = 0; j < 8; ++j) {
            const int tap = quad * 8 + j;
            woff[j] = (tap < 25) ? ((tap / 5) << 5) + (tap % 5) : 0;
        }
        const unsigned kmask = (quad == 3) ? 0u : 0xFFFFFFFFu;

        for (int tl = wave; tl < 49; tl += 4) {
            const int pb4 = tl * 4 + colq;                // pool block 0..195
            const int bh  = (pb4 * 4682) >> 16;           // pb4 / 14
            const int bw  = pb4 - bh * 14;
            const int base = (bh << 6) + (bw << 1) + soff; // oh*32 + ow
            unsigned v0 = sxb[base + woff[0]];
            unsigned v1 = sxb[base + woff[1]] & kmask;
            unsigned v2 = sxb[base + woff[2]] & kmask;
            unsigned v3 = sxb[base + woff[3]] & kmask;
            unsigned v4 = sxb[base + woff[4]] & kmask;
            unsigned v5 = sxb[base + woff[5]] & kmask;
            unsigned v6 = sxb[base + woff[6]] & kmask;
            unsigned v7 = sxb[base + woff[7]] & kmask;
            uint4 u;
            u.x = v0 | (v1 << 16);
            u.y = v2 | (v3 << 16);
            u.z = v4 | (v5 << 16);
            u.w = v6 | (v7 << 16);
            const bf16x8 af = *(const bf16x8*)&u;
            f32x4 z = {};
            f32x4 c0 = __builtin_amdgcn_mfma_f32_16x16x32_bf16(af, B0, z, 0, 0, 0);
            f32x4 c1 = __builtin_amdgcn_mfma_f32_16x16x32_bf16(af, B1, z, 0, 0, 0);
            // quad's 4 C-rows = one 2x2 pool window (subs 0..3); bf16-round
            // the h-pool maxima first (bit-exact), then v-max, alpha/bias/tanh.
            const int pos2 = tl * 4 + quad;
            const float h01 = bf2f(f2bf(fmaxf(c0[0], c0[1])));
            const float h23 = bf2f(f2bf(fmaxf(c0[2], c0[3])));
            sxt[pos2 * 40 + col] =
                f2bf(tanh_fast(fmaf(a1, fmaxf(h01, h23), b1a)));
            const float g01 = bf2f(f2bf(fmaxf(c1[0], c1[1])));
            const float g23 = bf2f(f2bf(fmaxf(c1[2], c1[3])));
            sxt[pos2 * 40 + col + 16] =
                f2bf(tanh_fast(fmaf(a1, fmaxf(g01, g23), b1b)));
        }
    }
    __syncthreads();

    // ---- conv2 MFMA (Z-ordered M) + fused pool/alpha/bias/tanh -> p2b ---
    const int n0  = (wave & 1) * 32;
    const int mt0 = (wave >> 1) * 4;
    f32x4 acc2[4][2] = {};
    conv2_all(w2b, sxt, n0, mt0, lane, acc2);

    {   // quad's 4 C-rows = one 2x2 pool window; chain
        // fmax(fmax(a0,a1), fmax(a2,a3)) identical to old hb2 path.
        const float a2 = salpha[1];
        const float b2a = b2[n0 + col];
        const float b2b = b2[n0 + 16 + col];
        ushort* prow = p2b + (size_t)n * 1600;
        #pragma unroll
        for (int mi = 0; mi < 4; ++mi) {
            const int pb25 = (mt0 + mi) * 4 + quad;
            if (pb25 < 25) {
                #pragma unroll
                for (int np = 0; np < 2; ++np) {
                    const float p01 = fmaxf(acc2[mi][np][0], acc2[mi][np][1]);
                    const float p23 = fmaxf(acc2[mi][np][2], acc2[mi][np][3]);
                    const float pooled = fmaxf(p01, p23);
                    const int oc = n0 + np * 16 + col;
                    const float bb = np ? b2b : b2a;
                    prow[oc * 25 + pb25] =
                        f2bf(tanh_fast(fmaf(a2, pooled, bb)));
                }
            }
        }
    }
}

// ---------------------------------------------------------------------------
// conv3fc v3: fused conv3 GEMM + fc1 + fc2 + softmax. 128 blocks x 1024 thr
// x 8 imgs (lanes 0..31 valid; pad lanes clamped — MFMA C-rows independent,
// valid rows bit-exact). SAME 13/13/12/12 K-chains and red-sum order.
// red lane-major [kg][nt][r][lane]: conflict-free. LDS ~80KB, 128 CUs busy.
__global__ __launch_bounds__(1024)
void conv3fc_kernel(const ushort* __restrict__ p2b, const ushort* __restrict__ w3b,
                    const float* __restrict__ b3, const float* __restrict__ pb,
                    const float* __restrict__ fw1t, const float* __restrict__ fb1,
                    const float* __restrict__ fw2t, const float* __restrict__ fb2,
                    float* __restrict__ out) {
    __shared__ __align__(16) char redmem[32768];     // red[4][8][4][64] f32
    __shared__ __align__(16) float h3s[8][120];
    __shared__ __align__(16) float fw1s[120 * 84];
    __shared__ __align__(16) float fw2s[84 * 10];
    __shared__ float salpha[3];
    float (*red)[8][4][64] = (float (*)[8][4][64])redmem;  // [kg][nt][r][lane]
    float* sh4 = (float*)redmem;                     // [8][84] overlay
    float* sl  = (float*)(redmem + 8 * 84 * 4);      // [8][10] overlay

    const int t = threadIdx.x;
    const int wave = t >> 6, lane = t & 63;
    const int col = lane & 15, quad = lane >> 4;
    const int img0 = blockIdx.x * 8;
    const int kg  = wave & 3;       // K-split index (sum order 0..3)
    const int ntg = wave >> 2;      // handles nt = ntg*2, ntg*2+1

    // stage fc weights (visibility covered by the post-conv3 barrier)
    for (int i = t; i < 2520; i += 1024)
        ((float4*)fw1s)[i] = ((const float4*)fw1t)[i];
    if (t < 210) ((float4*)fw2s)[t] = ((const float4*)fw2t)[t];
    if (t == 0) salpha[0] = alpha_of(pb, 2);
    if (t == 1) salpha[1] = alpha_of(pb, 3);
    if (t == 2) salpha[2] = alpha_of(pb, 4);

    // ---- conv3 MFMA: 8 imgs (+8 pad rows) x 2 nt-tiles per wave ---------
    const int kstart = (kg < 2) ? kg * 13 : 26 + (kg - 2) * 12;  // 0,13,26,38
    const int steps  = (kg < 2) ? 13 : 12;
    const int acol   = (col < 8) ? col : 7;          // clamp pad images
    const ushort* Abase = p2b + (size_t)(img0 + acol) * 1600 + kstart * 32 + quad * 8;

    f32x4 acc[2] = {};
    {
        const int nt0 = ntg * 2;
        const ushort* Bb0 = w3b + (size_t)(nt0 * 16 + col) * 1600 + kstart * 32 + quad * 8;
        const ushort* Bb1 = Bb0 + (size_t)16 * 1600;
        for (int s = 0; s < steps; ++s) {
            const bf16x8 af = *(const bf16x8*)(Abase + s * 32);
            const bf16x8 b0 = *(const bf16x8*)(Bb0 + s * 32);
            const bf16x8 b1 = *(const bf16x8*)(Bb1 + s * 32);
            acc[0] = __builtin_amdgcn_mfma_f32_16x16x32_bf16(af, b0, acc[0], 0, 0, 0);
            acc[1] = __builtin_amdgcn_mfma_f32_16x16x32_bf16(af, b1, acc[1], 0, 0, 0);
        }
        #pragma unroll
        for (int j = 0; j < 2; ++j)
            #pragma unroll
            for (int r = 0; r < 4; ++r)
                red[kg][nt0 + j][r][lane] = acc[j][r];
    }
    __syncthreads();

    // ---- cross-wave reduce + alpha/bias/tanh -> h3s ---------------------
    {
        const float a3 = salpha[0];
        const int nt  = t >> 7;
        const int rem = t & 127;
        const int vh  = rem >> 5;
        const int l   = rem & 31;              // lanes 0..31
        const int img = ((l >> 4) << 2) + vh;  // 0..7
        const int oc  = (nt << 4) + (l & 15);
        if (oc < 120) {
            float s = red[0][nt][vh][l] + red[1][nt][vh][l]
                    + red[2][nt][vh][l] + red[3][nt][vh][l];
            h3s[img][oc] = tanh_fast(fmaf(a3, s, b3[oc]));
        }
    }
    __syncthreads();

    // ---- fc1: 672 tasks (8 img x 84 oc), k 0..119 ascending -------------
    if (t < 672) {
        const float af1 = salpha[1];
        const int img = t / 84, oc = t - img * 84;
        float a = 0.f;
        #pragma unroll 4
        for (int k = 0; k < 120; ++k)
            a = fmaf(fw1s[k * 84 + oc], h3s[img][k], a);
        sh4[img * 84 + oc] = tanh_fast(fmaf(af1, a, fb1[oc]));
    }
    __syncthreads();

    // ---- fc2 + logits ---------------------------------------------------
    if (t < 80) {
        const float af2 = salpha[2];
        const int img = t / 10, oc = t - img * 10;
        float a2 = 0.f;
        #pragma unroll 4
        for (int k = 0; k < 84; ++k)
            a2 = fmaf(fw2s[k * 10 + oc], sh4[img * 84 + k], a2);
        const float lg = fmaf(af2, a2, fb2[oc]);
        sl[img * 10 + oc] = lg;
        out[(size_t)(img0 + img) * 10 + oc] = lg;
    }
    __syncthreads();

    // ---- softmax --------------------------------------------------------
    if (t < 80) {
        const int img = t / 10, oc = t - img * 10;
        float m = -INFINITY;
        #pragma unroll
        for (int i = 0; i < 10; ++i) m = fmaxf(m, sl[img * 10 + i]);
        float s = 0.f;
        #pragma unroll
        for (int i = 0; i < 10; ++i) s += expf(sl[img * 10 + i] - m);
        out[10240 + (size_t)(img0 + img) * 10 + oc] = expf(sl[img * 10 + oc] - m) / s;
    }
}

// ---------------------------------------------------------------------------
extern "C" void kernel_launch(void* const* d_in, const int* in_sizes, int n_in,
                              void* d_out, int out_size, void* d_ws, size_t ws_size,
                              hipStream_t stream) {
    const float* x   = (const float*)d_in[0];
    const float* w1  = (const float*)d_in[1];
    const float* b1  = (const float*)d_in[2];
    const float* w2  = (const float*)d_in[3];
    const float* b2  = (const float*)d_in[4];
    const float* w3  = (const float*)d_in[5];
    const float* b3  = (const float*)d_in[6];
    const float* fw1 = (const float*)d_in[7];
    const float* fb1 = (const float*)d_in[8];
    const float* fw2 = (const float*)d_in[9];
    const float* fb2 = (const float*)d_in[10];

    float* ws = (float*)d_ws;
    float*    pb    = ws + OFF_PB;
    ushort*   w1b   = (ushort*)(ws + OFF_W1B);
    ushort*   w2b   = (ushort*)(ws + OFF_W2B);
    ushort*   w3b   = (ushort*)(ws + OFF_W3B);
    float*    fw1t  = ws + OFF_FW1T;
    float*    fw2t  = ws + OFF_FW2T;
    ushort*   p2b   = (ushort*)(ws + OFF_P2B);
    unsigned* flags = (unsigned*)(ws + OFF_FLAGS);
    float*    out   = (float*)d_out;

    tern01_kernel<<<32, 256, 0, stream>>>(w1, w2, w1b, w2b, pb, flags);
    conv12_kernel<<<1072, 256, 0, stream>>>(x, w1b, b1, w2b, b2, pb, p2b,
                                            w3, fw1, fw2, w3b, fw1t, fw2t,
                                            flags);
    conv3fc_kernel<<<128, 1024, 0, stream>>>(p2b, w3b, b3, pb,
                                             fw1t, fb1, fw2t, fb2, out);
}